// Round 1
// baseline (979.496 us; speedup 1.0000x reference)
//
#include <hip/hip_runtime.h>

#define K 8192
#define NROWS 8192
#define NSTEPS 100
#define QEPS 1.1920928955078125e-07f

__global__ __launch_bounds__(256) void mse_observer_kernel(
    const float* __restrict__ x, float* __restrict__ out)
{
    const int row  = blockIdx.x;
    const int tid  = threadIdx.x;
    const int lane = tid & 63;
    const int wave = tid >> 6;

    const float4* xr = reinterpret_cast<const float4*>(x + (size_t)row * K);

    // Load 32 elements per thread (8 x float4, coalesced), keep in registers.
    float xv[32];
    #pragma unroll
    for (int j = 0; j < 8; ++j) {
        float4 v = xr[tid + j * 256];
        xv[j * 4 + 0] = v.x;
        xv[j * 4 + 1] = v.y;
        xv[j * 4 + 2] = v.z;
        xv[j * 4 + 3] = v.w;
    }

    // Per-thread min/max
    float vmin = xv[0], vmax = xv[0];
    #pragma unroll
    for (int e = 1; e < 32; ++e) {
        vmin = fminf(vmin, xv[e]);
        vmax = fmaxf(vmax, xv[e]);
    }
    // Wave (64-lane) reduce
    #pragma unroll
    for (int off = 32; off >= 1; off >>= 1) {
        vmin = fminf(vmin, __shfl_xor(vmin, off));
        vmax = fmaxf(vmax, __shfl_xor(vmax, off));
    }

    __shared__ float smin[4], smax[4];
    __shared__ float partial[NSTEPS * 4];
    __shared__ float sloss[NSTEPS];

    if (lane == 0) { smin[wave] = vmin; smax[wave] = vmax; }
    __syncthreads();

    const float rmin  = fminf(fminf(smin[0], smin[1]), fminf(smin[2], smin[3]));
    const float rmax  = fmaxf(fmaxf(smax[0], smax[1]), fmaxf(smax[2], smax[3]));
    const float range = fmaxf(fabsf(rmin), rmax);
    const float rstep = range / (float)NSTEPS;   // matches range_val / STEPS

    // 100 candidate thresholds; loss accumulated per wave, stored to LDS.
    for (int i = 1; i <= NSTEPS; ++i) {
        const float thres = rstep * (float)i;
        const float s     = fmaxf(thres / 127.5f, QEPS);
        const float inv_s = 1.0f / s;
        float acc = 0.0f;
        #pragma unroll
        for (int e = 0; e < 32; ++e) {
            float q = __builtin_amdgcn_fmed3f(
                __builtin_rintf(xv[e] * inv_s), -128.0f, 127.0f);
            float d = __builtin_fmaf(q, s, -xv[e]);   // q*s - x, fused
            acc = __builtin_fmaf(d, d, acc);
        }
        // Wave reduce sum
        #pragma unroll
        for (int off = 32; off >= 1; off >>= 1) acc += __shfl_xor(acc, off);
        if (lane == 0) partial[(i - 1) * 4 + wave] = acc;  // own slot, no race
    }
    __syncthreads();

    // Combine wave partials (sum over row; mean = sum * 2^-13 exact, argmin same)
    if (tid < NSTEPS) {
        sloss[tid] = (partial[tid * 4 + 0] + partial[tid * 4 + 1]) +
                     (partial[tid * 4 + 2] + partial[tid * 4 + 3]);
    }
    __syncthreads();

    if (tid == 0) {
        float opt = 3.4e38f;
        int best = 0;
        #pragma unroll 1
        for (int i = 0; i < NSTEPS; ++i) {
            float l = sloss[i];
            if (l < opt) { opt = l; best = i; }   // strict <: earliest min
        }
        const float tbest = rstep * (float)(best + 1);
        out[row]         = -tbest;   // min_val
        out[NROWS + row] =  tbest;   // max_val
    }
}

extern "C" void kernel_launch(void* const* d_in, const int* in_sizes, int n_in,
                              void* d_out, int out_size, void* d_ws, size_t ws_size,
                              hipStream_t stream) {
    const float* x = (const float*)d_in[0];
    float* out = (float*)d_out;
    mse_observer_kernel<<<NROWS, 256, 0, stream>>>(x, out);
}